// Round 1
// baseline (540.651 us; speedup 1.0000x reference)
//
#include <hip/hip_runtime.h>
#include <hip/hip_bf16.h>
#include <stdint.h>

typedef __bf16 bf16x8 __attribute__((ext_vector_type(8)));
typedef float f32x4 __attribute__((ext_vector_type(4)));

// ---------------- helpers ----------------

__device__ __forceinline__ void gld_lds16(const void* g, void* l) {
  // global -> LDS direct DMA, 16B per lane. LDS dest must be wave-uniform
  // base + lane*16 (layout below guarantees this).
  __builtin_amdgcn_global_load_lds(
      (const __attribute__((address_space(1))) unsigned int*)g,
      (__attribute__((address_space(3))) unsigned int*)l, 16, 0, 0);
}

__device__ __forceinline__ uint16_t f2bf(float f) {
  // round-to-nearest-even bf16 (inputs are well-scaled normals; no NaN/Inf)
  uint32_t u = __float_as_uint(f);
  return (uint16_t)((u + 0x7fffu + ((u >> 16) & 1u)) >> 16);
}

__device__ __forceinline__ uint32_t pk2(float a, float b) {
  return (uint32_t)f2bf(a) | ((uint32_t)f2bf(b) << 16);
}

// ---------------- cast fp32 -> bf16, with optional K padding ----------------
// Each thread produces 8 contiguous bf16 outputs (one 16B store).
__global__ void cast_pad_kernel(const float* __restrict__ in,
                                uint16_t* __restrict__ out,
                                int rows, int cin, int cout) {
  int64_t idx = (int64_t)blockIdx.x * 256 + threadIdx.x;
  int perRow = cout >> 3;
  int64_t total = (int64_t)rows * perRow;
  if (idx >= total) return;
  int r = (int)(idx / perRow);
  int k = ((int)(idx % perRow)) << 3;
  uint4 v;
  if (k < cin) {  // cin % 8 == 0 for all our uses, so never straddles
    const float4* p = (const float4*)(in + (int64_t)r * cin + k);
    float4 f0 = p[0], f1 = p[1];
    v = make_uint4(pk2(f0.x, f0.y), pk2(f0.z, f0.w),
                   pk2(f1.x, f1.y), pk2(f1.z, f1.w));
  } else {
    v = make_uint4(0u, 0u, 0u, 0u);  // K padding: exact zeros
  }
  *(uint4*)(out + (int64_t)r * cout + k) = v;
}

// ---------------- CM [t][h][k] fp32 -> CMT [t][k][h] bf16 ----------------
__global__ void transpose_cm(const float* __restrict__ CM,
                             uint16_t* __restrict__ CMT) {
  __shared__ float tile[32 * 33];  // +1 pad breaks bank conflicts
  const int t = blockIdx.z;
  const int hb = blockIdx.y * 32;
  const int kb = blockIdx.x * 32;
  const float* src = CM + ((int64_t)t * 512 + hb) * 512 + kb;
#pragma unroll
  for (int p = 0; p < 4; ++p) {
    int e = p * 256 + threadIdx.x;
    int i = e >> 5, j = e & 31;
    tile[i * 33 + j] = src[(int64_t)i * 512 + j];
  }
  __syncthreads();
  uint16_t* dst = CMT + ((int64_t)t * 512 + kb) * 512 + hb;
#pragma unroll
  for (int p = 0; p < 4; ++p) {
    int e = p * 256 + threadIdx.x;
    int i = e >> 5, j = e & 31;
    dst[(int64_t)i * 512 + j] = f2bf(tile[j * 33 + i]);
  }
}

// ---------------- GEMM1: C[M,N] = A[M,K] * B[N,K]^T + bias[N] ----------------
// m97 structure: 128x128 tile, BK=64, 4 waves (2x2) of 64x64 each.
__global__ __launch_bounds__(256, 2) void gemm_bt_bias(
    const uint16_t* __restrict__ A, const uint16_t* __restrict__ Bm,
    const float* __restrict__ bias, float* __restrict__ C,
    int M, int N, int K) {
  __shared__ __align__(16) uint16_t As[128 * 64];
  __shared__ __align__(16) uint16_t Bs[128 * 64];
  const int tid = threadIdx.x;
  const int lane = tid & 63;
  const int wid = tid >> 6;
  const int wm = wid >> 1, wn = wid & 1;
  const int m0 = blockIdx.x * 128;  // x = M so each block owns a unique A stripe
  const int n0 = blockIdx.y * 128;

  const int srow = tid >> 3;          // staging row within tile (8 threads/row)
  const int skk = (tid & 7) << 3;     // staging k offset (8 elems = 16B)
  const uint16_t* Ab = A + (int64_t)(m0 + srow) * K + skk;
  const uint16_t* Bb = Bm + (int64_t)(n0 + srow) * K + skk;

  const int lrow = lane & 15;
  const int lk = (lane >> 4) << 3;

  f32x4 acc[4][4] = {};

  for (int kt = 0; kt < K; kt += 64) {
#pragma unroll
    for (int p = 0; p < 4; ++p)
      gld_lds16(Ab + (int64_t)(p * 32) * K + kt, &As[(p * 256 + tid) * 8]);
#pragma unroll
    for (int p = 0; p < 4; ++p)
      gld_lds16(Bb + (int64_t)(p * 32) * K + kt, &Bs[(p * 256 + tid) * 8]);
    __syncthreads();
#pragma unroll
    for (int ks = 0; ks < 2; ++ks) {
      bf16x8 af[4], bfr[4];
#pragma unroll
      for (int i = 0; i < 4; ++i)
        af[i] = *(const bf16x8*)&As[(wm * 64 + i * 16 + lrow) * 64 + ks * 32 + lk];
#pragma unroll
      for (int j = 0; j < 4; ++j)
        bfr[j] = *(const bf16x8*)&Bs[(wn * 64 + j * 16 + lrow) * 64 + ks * 32 + lk];
#pragma unroll
      for (int i = 0; i < 4; ++i)
#pragma unroll
        for (int j = 0; j < 4; ++j)
          acc[i][j] = __builtin_amdgcn_mfma_f32_16x16x32_bf16(af[i], bfr[j],
                                                              acc[i][j], 0, 0, 0);
    }
    __syncthreads();
  }

  const int r0 = (lane >> 4) << 2;
#pragma unroll
  for (int i = 0; i < 4; ++i) {
    int row = m0 + wm * 64 + i * 16 + r0;
#pragma unroll
    for (int j = 0; j < 4; ++j) {
      int col = n0 + wn * 64 + j * 16 + (lane & 15);
      float bv = bias ? bias[col] : 0.0f;
      float* cp = C + (int64_t)row * N + col;
#pragma unroll
      for (int r = 0; r < 4; ++r) cp[(int64_t)r * N] = acc[i][j][r] + bv;
    }
  }
}

// ---------------- fused mixture GEMM ----------------
// C[b,k] = sum_t W[b,t] * sum_h X[b,h] * CMT[t][k][h]
__global__ __launch_bounds__(256, 2) void gemm_mix(
    const uint16_t* __restrict__ X,    // [M][512] bf16
    const uint16_t* __restrict__ CMT,  // [16][512][512] bf16 (t,k,h)
    const float* __restrict__ Wt,      // [M][16]
    float* __restrict__ C) {           // [M][512]
  __shared__ __align__(16) uint16_t As[128 * 64];
  __shared__ __align__(16) uint16_t Bs[128 * 64];
  __shared__ float ws[128 * 16];
  const int tid = threadIdx.x;
  const int lane = tid & 63;
  const int wid = tid >> 6;
  const int wm = wid >> 1, wn = wid & 1;
  const int m0 = blockIdx.x * 128;
  const int n0 = blockIdx.y * 128;

#pragma unroll
  for (int p = 0; p < 8; ++p) {  // stage the 128x16 softmax-weight block
    int e = p * 256 + tid;
    ws[e] = Wt[(int64_t)m0 * 16 + e];
  }

  const int srow = tid >> 3;
  const int skk = (tid & 7) << 3;
  const uint16_t* Ab = X + (int64_t)(m0 + srow) * 512 + skk;

  const int lrow = lane & 15;
  const int lk = (lane >> 4) << 3;
  const int r0 = (lane >> 4) << 2;

  f32x4 accF[4][4] = {};

#pragma unroll 1
  for (int t = 0; t < 16; ++t) {
    f32x4 acc[4][4] = {};
    const uint16_t* Bb =
        CMT + (int64_t)t * 512 * 512 + (int64_t)(n0 + srow) * 512 + skk;
#pragma unroll 1
    for (int ht = 0; ht < 8; ++ht) {
      const int kt = ht * 64;
#pragma unroll
      for (int p = 0; p < 4; ++p)
        gld_lds16(Ab + (p * 32) * 512 + kt, &As[(p * 256 + tid) * 8]);
#pragma unroll
      for (int p = 0; p < 4; ++p)
        gld_lds16(Bb + (p * 32) * 512 + kt, &Bs[(p * 256 + tid) * 8]);
      __syncthreads();
#pragma unroll
      for (int ks = 0; ks < 2; ++ks) {
        bf16x8 af[4], bfr[4];
#pragma unroll
        for (int i = 0; i < 4; ++i)
          af[i] = *(const bf16x8*)&As[(wm * 64 + i * 16 + lrow) * 64 + ks * 32 + lk];
#pragma unroll
        for (int j = 0; j < 4; ++j)
          bfr[j] = *(const bf16x8*)&Bs[(wn * 64 + j * 16 + lrow) * 64 + ks * 32 + lk];
#pragma unroll
        for (int i = 0; i < 4; ++i)
#pragma unroll
          for (int j = 0; j < 4; ++j)
            acc[i][j] = __builtin_amdgcn_mfma_f32_16x16x32_bf16(
                af[i], bfr[j], acc[i][j], 0, 0, 0);
      }
      __syncthreads();
    }
    // accF += w[row,t] * acc   (row = m-row of each accumulator register)
#pragma unroll
    for (int i = 0; i < 4; ++i) {
      int rb = wm * 64 + i * 16 + r0;
      float wv0 = ws[(rb + 0) * 16 + t];
      float wv1 = ws[(rb + 1) * 16 + t];
      float wv2 = ws[(rb + 2) * 16 + t];
      float wv3 = ws[(rb + 3) * 16 + t];
#pragma unroll
      for (int j = 0; j < 4; ++j) {
        accF[i][j][0] += wv0 * acc[i][j][0];
        accF[i][j][1] += wv1 * acc[i][j][1];
        accF[i][j][2] += wv2 * acc[i][j][2];
        accF[i][j][3] += wv3 * acc[i][j][3];
      }
    }
  }

#pragma unroll
  for (int i = 0; i < 4; ++i) {
    int row = m0 + wm * 64 + i * 16 + r0;
#pragma unroll
    for (int j = 0; j < 4; ++j) {
      int col = n0 + wn * 64 + j * 16 + (lane & 15);
      float* cp = C + (int64_t)row * 512 + col;
#pragma unroll
      for (int r = 0; r < 4; ++r) cp[(int64_t)r * 512] = accF[i][j][r];
    }
  }
}

// ---------------- scores = mlp_out @ attn ; softmax over T=16 ----------------
// wave handles 4 rows: lane = 4bit row-group | 4bit task index
__global__ __launch_bounds__(256) void attn_softmax(
    const float* __restrict__ mlp_out, const float* __restrict__ attn,
    float* __restrict__ W) {
  __shared__ float xs[16 * 512];   // 16 batch rows
  __shared__ float as_[512 * 16];  // attn [h][t]
  const int tid = threadIdx.x;
  const int b0 = blockIdx.x * 16;
#pragma unroll
  for (int p = 0; p < 8; ++p) {
    int e4 = p * 256 + tid;
    ((float4*)xs)[e4] = ((const float4*)(mlp_out + (int64_t)b0 * 512))[e4];
    ((float4*)as_)[e4] = ((const float4*)attn)[e4];
  }
  __syncthreads();
  const int lane = tid & 63, w = tid >> 6;
  const int bl = w * 4 + (lane >> 4);
  const int t = lane & 15;
  const float* xrow = xs + bl * 512;
  float s = 0.f;
#pragma unroll 8
  for (int h = 0; h < 512; ++h) s += xrow[h] * as_[h * 16 + t];
  float m = s;
#pragma unroll
  for (int o = 8; o >= 1; o >>= 1) m = fmaxf(m, __shfl_xor(m, o));
  float e = __expf(s - m);
  float sum = e;
#pragma unroll
  for (int o = 8; o >= 1; o >>= 1) sum += __shfl_xor(sum, o);
  W[(int64_t)(b0 + bl) * 16 + t] = e / sum;
}

// ---------------- sigmoid(out1 @ cla_w^T + cla_b) ----------------
__global__ __launch_bounds__(256) void classify(
    const float* __restrict__ out1, const float* __restrict__ cla_w,
    const float* __restrict__ cla_b, float* __restrict__ out) {
  const int tid = threadIdx.x, lane = tid & 63, w = tid >> 6;
  const int b = blockIdx.x * 4 + w;
  const float4* row = (const float4*)(out1 + (int64_t)b * 512);
  const float4* cw = (const float4*)cla_w;
  float4 x0 = row[lane * 2], x1 = row[lane * 2 + 1];
  float4 w0 = cw[lane * 2], w1 = cw[lane * 2 + 1];
  float s = x0.x * w0.x + x0.y * w0.y + x0.z * w0.z + x0.w * w0.w +
            x1.x * w1.x + x1.y * w1.y + x1.z * w1.z + x1.w * w1.w;
#pragma unroll
  for (int o = 32; o >= 1; o >>= 1) s += __shfl_xor(s, o);
  if (lane == 0) out[b] = 1.f / (1.f + __expf(-(s + cla_b[0])));
}

// ---------------- launch ----------------
extern "C" void kernel_launch(void* const* d_in, const int* in_sizes, int n_in,
                              void* d_out, int out_size, void* d_ws,
                              size_t ws_size, hipStream_t stream) {
  const float* data = (const float*)d_in[0];   // [8192][5000]
  const float* mlp_w = (const float*)d_in[1];  // [512][5000]
  const float* mlp_b = (const float*)d_in[2];  // [512]
  const float* CM = (const float*)d_in[3];     // [16][512][512]
  const float* attn = (const float*)d_in[4];   // [512][16]
  const float* cla_w = (const float*)d_in[5];  // [512]
  const float* cla_b = (const float*)d_in[6];  // [1]
  float* out = (float*)d_out;                  // [8192]

  char* ws = (char*)d_ws;
  // long-lived:
  uint16_t* Xb = (uint16_t*)(ws + 0);                   // 8192*5120*2 = 83,886,080
  uint16_t* Wb = (uint16_t*)(ws + 83886080);            // 512*5120*2  =  5,242,880
  float* MO = (float*)(ws + 89128960);                  // 8192*512*4  = 16,777,216
  // overlay region (reuses Xb after gemm1 has consumed it; stream-ordered):
  float* Wsm = (float*)(ws + 0);                        // 8192*16*4 = 524,288
  uint16_t* X16 = (uint16_t*)(ws + 524288);             // 8192*512*2 = 8,388,608
  uint16_t* CMT = (uint16_t*)(ws + 8912896);            // 16*512*512*2 = 8,388,608
  float* O1 = (float*)(ws + 17301504);                  // 8192*512*4 = 16,777,216
  // total required: 105,906,176 bytes

  // 1) cast inputs to bf16, pad K 5000 -> 5120 with zeros
  cast_pad_kernel<<<20480, 256, 0, stream>>>(data, Xb, 8192, 5000, 5120);
  cast_pad_kernel<<<1280, 256, 0, stream>>>(mlp_w, Wb, 512, 5000, 5120);
  // 2) mlp_out = data @ mlp_w.T + mlp_b   (fp32 out)
  gemm_bt_bias<<<dim3(64, 4), 256, 0, stream>>>(Xb, Wb, mlp_b, MO, 8192, 512, 5120);
  // 3) CM -> CMT bf16 (t,k,h)   [after gemm1: lives in Xb overlay]
  transpose_cm<<<dim3(16, 16, 16), 256, 0, stream>>>(CM, CMT);
  // 4) softmax weights
  attn_softmax<<<512, 256, 0, stream>>>(MO, attn, Wsm);
  // 5) mlp_out -> bf16
  cast_pad_kernel<<<2048, 256, 0, stream>>>(MO, X16, 8192, 512, 512);
  // 6) fused mixture GEMM
  gemm_mix<<<dim3(64, 4), 256, 0, stream>>>(X16, CMT, Wsm, O1);
  // 7) classifier + sigmoid
  classify<<<2048, 256, 0, stream>>>(O1, cla_w, cla_b, out);
}

// Round 2
// 482.411 us; speedup vs baseline: 1.1207x; 1.1207x over previous
//
#include <hip/hip_runtime.h>
#include <hip/hip_bf16.h>
#include <stdint.h>

typedef __bf16 bf16x8 __attribute__((ext_vector_type(8)));
typedef float f32x4 __attribute__((ext_vector_type(4)));

// ---------------- helpers ----------------

__device__ __forceinline__ void gld_lds16(const void* g, void* l) {
  // global -> LDS direct DMA, 16B per lane. LDS dest must be wave-uniform
  // base + lane*16 (layouts below guarantee this).
  __builtin_amdgcn_global_load_lds(
      (const __attribute__((address_space(1))) unsigned int*)g,
      (__attribute__((address_space(3))) unsigned int*)l, 16, 0, 0);
}

__device__ __forceinline__ uint16_t f2bf(float f) {
  uint32_t u = __float_as_uint(f);
  return (uint16_t)((u + 0x7fffu + ((u >> 16) & 1u)) >> 16);
}

__device__ __forceinline__ uint32_t pk2(float a, float b) {
  return (uint32_t)f2bf(a) | ((uint32_t)f2bf(b) << 16);
}

// ---------------- cast fp32 -> bf16, with optional K padding ----------------
__global__ void cast_pad_kernel(const float* __restrict__ in,
                                uint16_t* __restrict__ out,
                                int rows, int cin, int cout) {
  int64_t idx = (int64_t)blockIdx.x * 256 + threadIdx.x;
  int perRow = cout >> 3;
  int64_t total = (int64_t)rows * perRow;
  if (idx >= total) return;
  int r = (int)(idx / perRow);
  int k = ((int)(idx % perRow)) << 3;
  uint4 v;
  if (k < cin) {
    const float4* p = (const float4*)(in + (int64_t)r * cin + k);
    float4 f0 = p[0], f1 = p[1];
    v = make_uint4(pk2(f0.x, f0.y), pk2(f0.z, f0.w),
                   pk2(f1.x, f1.y), pk2(f1.z, f1.w));
  } else {
    v = make_uint4(0u, 0u, 0u, 0u);
  }
  *(uint4*)(out + (int64_t)r * cout + k) = v;
}

// ---------------- CM [t][h][k] fp32 -> CMT [t][k][h] bf16 ----------------
__global__ void transpose_cm(const float* __restrict__ CM,
                             uint16_t* __restrict__ CMT) {
  __shared__ float tile[32 * 33];
  const int t = blockIdx.z;
  const int hb = blockIdx.y * 32;
  const int kb = blockIdx.x * 32;
  const float* src = CM + ((int64_t)t * 512 + hb) * 512 + kb;
#pragma unroll
  for (int p = 0; p < 4; ++p) {
    int e = p * 256 + threadIdx.x;
    int i = e >> 5, j = e & 31;
    tile[i * 33 + j] = src[(int64_t)i * 512 + j];
  }
  __syncthreads();
  uint16_t* dst = CMT + ((int64_t)t * 512 + kb) * 512 + hb;
#pragma unroll
  for (int p = 0; p < 4; ++p) {
    int e = p * 256 + threadIdx.x;
    int i = e >> 5, j = e & 31;
    dst[(int64_t)i * 512 + j] = f2bf(tile[j * 33 + i]);
  }
}

// ---------------- MO[b][n] = bias[n] (so K-split blocks can atomicAdd) ------
__global__ void init_bias(const float* __restrict__ bias,
                          float* __restrict__ MO) {
  int i = blockIdx.x * 256 + threadIdx.x;  // over 8192*128 float4s
  float4 bv = ((const float4*)bias)[i & 127];
  ((float4*)MO)[i] = bv;
}

// ---------------- GEMM1 (K-split): C += A[M,K] * B[N,K]^T ----------------
// 128x128 tile, BK=64, 4 waves 2x2. XOR-swizzled LDS (col c stored at
// c^(row&7)) to break the 16-lane bank-quad conflict on fragment reads.
__global__ __launch_bounds__(256, 2) void gemm1_split(
    const uint16_t* __restrict__ A, const uint16_t* __restrict__ Bm,
    float* __restrict__ C, int M, int N, int K, int kChunk) {
  __shared__ __align__(16) uint16_t As[128 * 64];
  __shared__ __align__(16) uint16_t Bs[128 * 64];
  const int tid = threadIdx.x;
  const int lane = tid & 63;
  const int wid = tid >> 6;
  const int wm = wid >> 1, wn = wid & 1;
  const int m0 = blockIdx.x * 128;
  const int n0 = blockIdx.y * 128;
  const int k0 = blockIdx.z * kChunk;

  const int srow = tid >> 3;
  const int skswz = ((tid & 7) ^ (srow & 7)) << 3;  // swizzled 16B-chunk col
  const uint16_t* Ab = A + (int64_t)(m0 + srow) * K + skswz;
  const uint16_t* Bb = Bm + (int64_t)(n0 + srow) * K + skswz;

  const int lrow = lane & 15;
  const int key = lrow & 7;
  const int kg = lane >> 4;

  f32x4 acc[4][4] = {};

  for (int kt = k0; kt < k0 + kChunk; kt += 64) {
#pragma unroll
    for (int p = 0; p < 4; ++p)
      gld_lds16(Ab + (int64_t)(p * 32) * K + kt, &As[(p * 256 + tid) * 8]);
#pragma unroll
    for (int p = 0; p < 4; ++p)
      gld_lds16(Bb + (int64_t)(p * 32) * K + kt, &Bs[(p * 256 + tid) * 8]);
    __syncthreads();
#pragma unroll
    for (int ks = 0; ks < 2; ++ks) {
      const int off = (((ks << 2) | kg) ^ key) << 3;
      bf16x8 af[4], bfr[4];
#pragma unroll
      for (int i = 0; i < 4; ++i)
        af[i] = *(const bf16x8*)&As[(wm * 64 + i * 16 + lrow) * 64 + off];
#pragma unroll
      for (int j = 0; j < 4; ++j)
        bfr[j] = *(const bf16x8*)&Bs[(wn * 64 + j * 16 + lrow) * 64 + off];
#pragma unroll
      for (int i = 0; i < 4; ++i)
#pragma unroll
        for (int j = 0; j < 4; ++j)
          acc[i][j] = __builtin_amdgcn_mfma_f32_16x16x32_bf16(af[i], bfr[j],
                                                              acc[i][j], 0, 0, 0);
    }
    __syncthreads();
  }

  const int r0 = (lane >> 4) << 2;
#pragma unroll
  for (int i = 0; i < 4; ++i) {
    int row = m0 + wm * 64 + i * 16 + r0;
#pragma unroll
    for (int j = 0; j < 4; ++j) {
      int col = n0 + wn * 64 + j * 16 + (lane & 15);
      float* cp = C + (int64_t)row * N + col;
#pragma unroll
      for (int r = 0; r < 4; ++r) unsafeAtomicAdd(&cp[(int64_t)r * N], acc[i][j][r]);
    }
  }
}

// ---------------- fused mixture GEMM (t-split: 4 tasks per block) ----------
// C[b,k] += sum_{t in z-chunk} W[b,t] * sum_h X[b,h] * CMT[t][k][h]
__global__ __launch_bounds__(256, 2) void gemm_mix_split(
    const uint16_t* __restrict__ X,    // [8192][512] bf16
    const uint16_t* __restrict__ CMT,  // [16][512][512] bf16 (t,k,h)
    const float* __restrict__ Wt,      // [8192][16]
    float* __restrict__ C) {           // [8192][512] (pre-zeroed)
  __shared__ __align__(16) uint16_t As[128 * 64];
  __shared__ __align__(16) uint16_t Bs[128 * 64];
  __shared__ float ws[128 * 4];
  const int tid = threadIdx.x;
  const int lane = tid & 63;
  const int wid = tid >> 6;
  const int wm = wid >> 1, wn = wid & 1;
  const int m0 = blockIdx.x * 128;
  const int n0 = blockIdx.y * 128;
  const int t0 = blockIdx.z * 4;

  // stage the 128x4 softmax-weight block for this z-chunk
  ws[tid] = Wt[(int64_t)(m0 + (tid >> 2)) * 16 + t0 + (tid & 3)];
  ws[tid + 256] = Wt[(int64_t)(m0 + 64 + (tid >> 2)) * 16 + t0 + (tid & 3)];

  const int srow = tid >> 3;
  const int skswz = ((tid & 7) ^ (srow & 7)) << 3;
  const uint16_t* Ab = X + (int64_t)(m0 + srow) * 512 + skswz;

  const int lrow = lane & 15;
  const int key = lrow & 7;
  const int kg = lane >> 4;
  const int r0 = (lane >> 4) << 2;

  f32x4 accF[4][4] = {};

#pragma unroll 1
  for (int tt = 0; tt < 4; ++tt) {
    f32x4 acc[4][4] = {};
    const uint16_t* Bb =
        CMT + ((int64_t)(t0 + tt) * 512 + n0 + srow) * 512 + skswz;
#pragma unroll 1
    for (int ht = 0; ht < 8; ++ht) {
      const int kt = ht * 64;
#pragma unroll
      for (int p = 0; p < 4; ++p)
        gld_lds16(Ab + (p * 32) * 512 + kt, &As[(p * 256 + tid) * 8]);
#pragma unroll
      for (int p = 0; p < 4; ++p)
        gld_lds16(Bb + (p * 32) * 512 + kt, &Bs[(p * 256 + tid) * 8]);
      __syncthreads();
#pragma unroll
      for (int ks = 0; ks < 2; ++ks) {
        const int off = (((ks << 2) | kg) ^ key) << 3;
        bf16x8 af[4], bfr[4];
#pragma unroll
        for (int i = 0; i < 4; ++i)
          af[i] = *(const bf16x8*)&As[(wm * 64 + i * 16 + lrow) * 64 + off];
#pragma unroll
        for (int j = 0; j < 4; ++j)
          bfr[j] = *(const bf16x8*)&Bs[(wn * 64 + j * 16 + lrow) * 64 + off];
#pragma unroll
        for (int i = 0; i < 4; ++i)
#pragma unroll
          for (int j = 0; j < 4; ++j)
            acc[i][j] = __builtin_amdgcn_mfma_f32_16x16x32_bf16(
                af[i], bfr[j], acc[i][j], 0, 0, 0);
      }
      __syncthreads();
    }
#pragma unroll
    for (int i = 0; i < 4; ++i) {
      int rb = wm * 64 + i * 16 + r0;
      float wv0 = ws[(rb + 0) * 4 + tt];
      float wv1 = ws[(rb + 1) * 4 + tt];
      float wv2 = ws[(rb + 2) * 4 + tt];
      float wv3 = ws[(rb + 3) * 4 + tt];
#pragma unroll
      for (int j = 0; j < 4; ++j) {
        accF[i][j][0] += wv0 * acc[i][j][0];
        accF[i][j][1] += wv1 * acc[i][j][1];
        accF[i][j][2] += wv2 * acc[i][j][2];
        accF[i][j][3] += wv3 * acc[i][j][3];
      }
    }
  }

#pragma unroll
  for (int i = 0; i < 4; ++i) {
    int row = m0 + wm * 64 + i * 16 + r0;
#pragma unroll
    for (int j = 0; j < 4; ++j) {
      int col = n0 + wn * 64 + j * 16 + (lane & 15);
      float* cp = C + (int64_t)row * 512 + col;
#pragma unroll
      for (int r = 0; r < 4; ++r)
        unsafeAtomicAdd(&cp[(int64_t)r * 512], accF[i][j][r]);
    }
  }
}

// ------- scores = mlp_out @ attn ; softmax over T=16 ; + bf16 cast of rows --
__global__ __launch_bounds__(256) void attn_softmax_cast(
    const float* __restrict__ mlp_out, const float* __restrict__ attn,
    float* __restrict__ W, uint16_t* __restrict__ X16) {
  __shared__ float xs[16 * 512];
  __shared__ float as_[512 * 16];
  const int tid = threadIdx.x;
  const int b0 = blockIdx.x * 16;
#pragma unroll
  for (int p = 0; p < 8; ++p) {
    int e4 = p * 256 + tid;
    ((float4*)xs)[e4] = ((const float4*)(mlp_out + (int64_t)b0 * 512))[e4];
    ((float4*)as_)[e4] = ((const float4*)attn)[e4];
  }
  __syncthreads();
  // emit bf16 copy of the 16 rows (fused cast): 1024 uint4, 4 per thread
#pragma unroll
  for (int p = 0; p < 4; ++p) {
    int e = p * 256 + tid;
    const float* s = xs + e * 8;
    uint4 v = make_uint4(pk2(s[0], s[1]), pk2(s[2], s[3]),
                         pk2(s[4], s[5]), pk2(s[6], s[7]));
    *(uint4*)(X16 + (int64_t)b0 * 512 + e * 8) = v;
  }
  const int lane = tid & 63, w = tid >> 6;
  const int bl = w * 4 + (lane >> 4);
  const int t = lane & 15;
  const float* xrow = xs + bl * 512;
  float s = 0.f;
#pragma unroll 8
  for (int h = 0; h < 512; ++h) s += xrow[h] * as_[h * 16 + t];
  float m = s;
#pragma unroll
  for (int o = 8; o >= 1; o >>= 1) m = fmaxf(m, __shfl_xor(m, o));
  float e = __expf(s - m);
  float sum = e;
#pragma unroll
  for (int o = 8; o >= 1; o >>= 1) sum += __shfl_xor(sum, o);
  W[(int64_t)(b0 + bl) * 16 + t] = e / sum;
}

// ---------------- sigmoid(out1 @ cla_w^T + cla_b) ----------------
__global__ __launch_bounds__(256) void classify(
    const float* __restrict__ out1, const float* __restrict__ cla_w,
    const float* __restrict__ cla_b, float* __restrict__ out) {
  const int tid = threadIdx.x, lane = tid & 63, w = tid >> 6;
  const int b = blockIdx.x * 4 + w;
  const float4* row = (const float4*)(out1 + (int64_t)b * 512);
  const float4* cw = (const float4*)cla_w;
  float4 x0 = row[lane * 2], x1 = row[lane * 2 + 1];
  float4 w0 = cw[lane * 2], w1 = cw[lane * 2 + 1];
  float s = x0.x * w0.x + x0.y * w0.y + x0.z * w0.z + x0.w * w0.w +
            x1.x * w1.x + x1.y * w1.y + x1.z * w1.z + x1.w * w1.w;
#pragma unroll
  for (int o = 32; o >= 1; o >>= 1) s += __shfl_xor(s, o);
  if (lane == 0) out[b] = 1.f / (1.f + __expf(-(s + cla_b[0])));
}

// ---------------- launch ----------------
extern "C" void kernel_launch(void* const* d_in, const int* in_sizes, int n_in,
                              void* d_out, int out_size, void* d_ws,
                              size_t ws_size, hipStream_t stream) {
  const float* data = (const float*)d_in[0];   // [8192][5000]
  const float* mlp_w = (const float*)d_in[1];  // [512][5000]
  const float* mlp_b = (const float*)d_in[2];  // [512]
  const float* CM = (const float*)d_in[3];     // [16][512][512]
  const float* attn = (const float*)d_in[4];   // [512][16]
  const float* cla_w = (const float*)d_in[5];  // [512]
  const float* cla_b = (const float*)d_in[6];  // [1]
  float* out = (float*)d_out;                  // [8192]

  char* ws = (char*)d_ws;
  // long-lived:
  uint16_t* Xb = (uint16_t*)(ws + 0);         // 8192*5120*2 = 83,886,080
  uint16_t* Wb = (uint16_t*)(ws + 83886080);  // 512*5120*2  =  5,242,880
  float* MO = (float*)(ws + 89128960);        // 8192*512*4  = 16,777,216
  // overlay (Xb+Wb region is dead after gemm1; all writes below are
  // stream-ordered after gemm1 completes):
  float* Wsm = (float*)(ws + 0);               // 8192*16*4   = 524,288
  uint16_t* X16 = (uint16_t*)(ws + 524288);    // 8192*512*2  = 8,388,608
  uint16_t* CMT = (uint16_t*)(ws + 8912896);   // 16*512*512*2= 8,388,608
  float* O1 = (float*)(ws + 17301504);         // 8192*512*4  = 16,777,216
  // total: 105,906,176 bytes

  // 1) casts (pad K 5000->5120 with zeros)
  cast_pad_kernel<<<20480, 256, 0, stream>>>(data, Xb, 8192, 5000, 5120);
  cast_pad_kernel<<<1280, 256, 0, stream>>>(mlp_w, Wb, 512, 5000, 5120);
  // 2) MO = bias (broadcast), then K-split GEMM1 accumulates atomically
  init_bias<<<4096, 256, 0, stream>>>(mlp_b, MO);
  gemm1_split<<<dim3(64, 4, 4), 256, 0, stream>>>(Xb, Wb, MO, 8192, 512, 5120, 1280);
  // 3) overlays become live only now
  hipMemsetAsync(O1, 0, 8192 * 512 * 4, stream);
  transpose_cm<<<dim3(16, 16, 16), 256, 0, stream>>>(CM, CMT);
  // 4) softmax weights + fused bf16 cast of mlp_out
  attn_softmax_cast<<<512, 256, 0, stream>>>(MO, attn, Wsm, X16);
  // 5) t-split fused mixture GEMM (atomic accumulate into O1)
  gemm_mix_split<<<dim3(64, 4, 4), 256, 0, stream>>>(X16, CMT, Wsm, O1);
  // 6) classifier + sigmoid
  classify<<<2048, 256, 0, stream>>>(O1, cla_w, cla_b, out);
}

// Round 3
// 377.901 us; speedup vs baseline: 1.4307x; 1.2766x over previous
//
#include <hip/hip_runtime.h>
#include <hip/hip_bf16.h>
#include <stdint.h>

typedef __bf16 bf16x8 __attribute__((ext_vector_type(8)));
typedef float f32x4 __attribute__((ext_vector_type(4)));

// ---------------- helpers ----------------

__device__ __forceinline__ void gld_lds16(const void* g, void* l) {
  // global -> LDS direct DMA, 16B per lane. LDS dest must be wave-uniform
  // base + lane*16 (layouts below guarantee this).
  __builtin_amdgcn_global_load_lds(
      (const __attribute__((address_space(1))) unsigned int*)g,
      (__attribute__((address_space(3))) unsigned int*)l, 16, 0, 0);
}

__device__ __forceinline__ uint16_t f2bf(float f) {
  uint32_t u = __float_as_uint(f);
  return (uint16_t)((u + 0x7fffu + ((u >> 16) & 1u)) >> 16);
}

__device__ __forceinline__ uint32_t pk2(float a, float b) {
  return (uint32_t)f2bf(a) | ((uint32_t)f2bf(b) << 16);
}

// ---------------- cast fp32 -> bf16, with K padding ----------------
__global__ void cast_pad_kernel(const float* __restrict__ in,
                                uint16_t* __restrict__ out,
                                int rows, int cin, int cout) {
  int64_t idx = (int64_t)blockIdx.x * 256 + threadIdx.x;
  int perRow = cout >> 3;
  int64_t total = (int64_t)rows * perRow;
  if (idx >= total) return;
  int r = (int)(idx / perRow);
  int k = ((int)(idx % perRow)) << 3;
  uint4 v;
  if (k < cin) {
    const float4* p = (const float4*)(in + (int64_t)r * cin + k);
    float4 f0 = p[0], f1 = p[1];
    v = make_uint4(pk2(f0.x, f0.y), pk2(f0.z, f0.w),
                   pk2(f1.x, f1.y), pk2(f1.z, f1.w));
  } else {
    v = make_uint4(0u, 0u, 0u, 0u);
  }
  *(uint4*)(out + (int64_t)r * cout + k) = v;
}

// ---------------- MO[b][n] = bias[n] (so K-split blocks can atomicAdd) ------
__global__ void init_bias(const float* __restrict__ bias,
                          float* __restrict__ MO) {
  int i = blockIdx.x * 256 + threadIdx.x;  // over 8192*128 float4s
  float4 bv = ((const float4*)bias)[i & 127];
  ((float4*)MO)[i] = bv;
}

// ---------------- GEMM1 (K-split): C += A[M,K] * B[N,K]^T ----------------
// 128x128 tile, BK=64, 4 waves 2x2, XOR-swizzled LDS (0 bank conflicts,
// verified round 2). 1D grid decoded so the 4 n-sibling blocks of one
// A-stripe are 8 linear IDs apart (same XCD under round-robin dispatch).
__global__ __launch_bounds__(256, 2) void gemm1_split(
    const uint16_t* __restrict__ A, const uint16_t* __restrict__ Bm,
    float* __restrict__ C, int M, int N, int K, int kChunk) {
  __shared__ __align__(16) uint16_t As[128 * 64];
  __shared__ __align__(16) uint16_t Bs[128 * 64];
  const int tid = threadIdx.x;
  const int lane = tid & 63;
  const int wid = tid >> 6;
  const int wm = wid >> 1, wn = wid & 1;

  const int lin = blockIdx.x;
  const int mlo = lin & 7;
  const int nbk = (lin >> 3) & 3;
  const int rest = lin >> 5;
  const int m0 = ((rest & 7) * 8 + mlo) * 128;
  const int n0 = nbk * 128;
  const int k0 = (rest >> 3) * kChunk;

  const int srow = tid >> 3;
  const int skswz = ((tid & 7) ^ (srow & 7)) << 3;  // swizzled 16B-chunk col
  const uint16_t* Ab = A + (int64_t)(m0 + srow) * K + skswz;
  const uint16_t* Bb = Bm + (int64_t)(n0 + srow) * K + skswz;

  const int lrow = lane & 15;
  const int key = lrow & 7;
  const int kg = lane >> 4;

  f32x4 acc[4][4] = {};

  for (int kt = k0; kt < k0 + kChunk; kt += 64) {
#pragma unroll
    for (int p = 0; p < 4; ++p)
      gld_lds16(Ab + (int64_t)(p * 32) * K + kt, &As[(p * 256 + tid) * 8]);
#pragma unroll
    for (int p = 0; p < 4; ++p)
      gld_lds16(Bb + (int64_t)(p * 32) * K + kt, &Bs[(p * 256 + tid) * 8]);
    __syncthreads();
#pragma unroll
    for (int ks = 0; ks < 2; ++ks) {
      const int off = (((ks << 2) | kg) ^ key) << 3;
      bf16x8 af[4], bfr[4];
#pragma unroll
      for (int i = 0; i < 4; ++i)
        af[i] = *(const bf16x8*)&As[(wm * 64 + i * 16 + lrow) * 64 + off];
#pragma unroll
      for (int j = 0; j < 4; ++j)
        bfr[j] = *(const bf16x8*)&Bs[(wn * 64 + j * 16 + lrow) * 64 + off];
#pragma unroll
      for (int i = 0; i < 4; ++i)
#pragma unroll
        for (int j = 0; j < 4; ++j)
          acc[i][j] = __builtin_amdgcn_mfma_f32_16x16x32_bf16(af[i], bfr[j],
                                                              acc[i][j], 0, 0, 0);
    }
    __syncthreads();
  }

  const int r0 = (lane >> 4) << 2;
#pragma unroll
  for (int i = 0; i < 4; ++i) {
    int row = m0 + wm * 64 + i * 16 + r0;
#pragma unroll
    for (int j = 0; j < 4; ++j) {
      int col = n0 + wn * 64 + j * 16 + (lane & 15);
      float* cp = C + (int64_t)row * N + col;
#pragma unroll
      for (int r = 0; r < 4; ++r) unsafeAtomicAdd(&cp[(int64_t)r * N], acc[i][j][r]);
    }
  }
}

// ---------------- V[h][t] = sum_k CM[t][h][k] * cla_w[k] ----------------
// One wave per (t,h) row: 512-wide fp32 dot, wave reduce.
__global__ __launch_bounds__(256) void cmv_kernel(const float* __restrict__ CM,
                                                  const float* __restrict__ cla_w,
                                                  float* __restrict__ Vs) {
  const int tid = threadIdx.x, lane = tid & 63, wid = tid >> 6;
  const int row = blockIdx.x * 4 + wid;  // 0..8191 = t*512 + h
  const float4* src = (const float4*)(CM + (int64_t)row * 512);
  const float4* cw = (const float4*)cla_w;
  float4 a0 = src[lane * 2], a1 = src[lane * 2 + 1];
  float4 w0 = cw[lane * 2], w1 = cw[lane * 2 + 1];
  float s = a0.x * w0.x + a0.y * w0.y + a0.z * w0.z + a0.w * w0.w +
            a1.x * w1.x + a1.y * w1.y + a1.z * w1.z + a1.w * w1.w;
#pragma unroll
  for (int o = 32; o >= 1; o >>= 1) s += __shfl_xor(s, o);
  if (lane == 0) {
    int t = row >> 9, h = row & 511;
    Vs[h * 16 + t] = s;
  }
}

// ------- fused epilogue: scores, softmax, y = x@V^T, sigmoid(w.y + b) -------
// Per block: 16 batch rows. Lane layout: bl = wave*4 + (lane>>4), t = lane&15.
// avs interleaves attn[h][t] (slot t) and V[h][t] (slot 16+t), staged in two
// 256-h phases to keep static LDS at exactly 64 KB.
__global__ __launch_bounds__(256) void attn_final(
    const float* __restrict__ MO, const float* __restrict__ attn,
    const float* __restrict__ Vs, const float* __restrict__ cla_b,
    float* __restrict__ out) {
  __shared__ float xs[16 * 512];   // 32 KB
  __shared__ float avs[256 * 32];  // 32 KB
  const int tid = threadIdx.x;
  const int b0 = blockIdx.x * 16;
  // stage x rows (fp32)
#pragma unroll
  for (int p = 0; p < 8; ++p) {
    int e4 = p * 256 + tid;
    ((float4*)xs)[e4] = ((const float4*)(MO + (int64_t)b0 * 512))[e4];
  }
  const int lane = tid & 63, w = tid >> 6;
  const int bl = w * 4 + (lane >> 4);
  const int t = lane & 15;
  const float* xr = xs + bl * 512;
  float s = 0.f, y = 0.f;
  for (int ph = 0; ph < 2; ++ph) {
    __syncthreads();  // protect avs from previous phase's readers
#pragma unroll
    for (int p = 0; p < 4; ++p) {
      int e4 = p * 256 + tid;           // 1024 float4 = 256 h-rows x 16
      int h = e4 >> 2, c = (e4 & 3) << 2;
      *(float4*)&avs[h * 32 + c] = ((const float4*)attn)[ph * 1024 + e4];
      *(float4*)&avs[h * 32 + 16 + c] = ((const float4*)Vs)[ph * 1024 + e4];
    }
    __syncthreads();
    const float* xp = xr + ph * 256;
#pragma unroll 4
    for (int h = 0; h < 256; ++h) {
      float xv = xp[h];
      s += xv * avs[h * 32 + t];
      y += xv * avs[h * 32 + 16 + t];
    }
  }
  // softmax over the 16-lane t-group, then sum_t w_t * y_t
  float m = s;
#pragma unroll
  for (int o = 8; o >= 1; o >>= 1) m = fmaxf(m, __shfl_xor(m, o));
  float e = __expf(s - m);
  float sum = e;
#pragma unroll
  for (int o = 8; o >= 1; o >>= 1) sum += __shfl_xor(sum, o);
  float val = (e / sum) * y;
#pragma unroll
  for (int o = 8; o >= 1; o >>= 1) val += __shfl_xor(val, o);
  if (t == 0) out[b0 + bl] = 1.f / (1.f + __expf(-(val + cla_b[0])));
}

// ---------------- launch ----------------
extern "C" void kernel_launch(void* const* d_in, const int* in_sizes, int n_in,
                              void* d_out, int out_size, void* d_ws,
                              size_t ws_size, hipStream_t stream) {
  const float* data = (const float*)d_in[0];   // [8192][5000]
  const float* mlp_w = (const float*)d_in[1];  // [512][5000]
  const float* mlp_b = (const float*)d_in[2];  // [512]
  const float* CM = (const float*)d_in[3];     // [16][512][512]
  const float* attn = (const float*)d_in[4];   // [512][16]
  const float* cla_w = (const float*)d_in[5];  // [512]
  const float* cla_b = (const float*)d_in[6];  // [1]
  float* out = (float*)d_out;                  // [8192]

  char* ws = (char*)d_ws;
  uint16_t* Xb = (uint16_t*)(ws + 0);         // 8192*5120*2 = 83,886,080
  uint16_t* Wb = (uint16_t*)(ws + 83886080);  // 512*5120*2  =  5,242,880
  float* MO = (float*)(ws + 89128960);        // 8192*512*4  = 16,777,216
  // overlay: Xb region is dead once gemm1 completes (stream-ordered)
  float* Vs = (float*)(ws + 0);               // 512*16*4 = 32,768
  // total: 105,906,176 bytes (same footprint as round 1/2)

  // 1) casts (pad K 5000->5120 with zeros)
  cast_pad_kernel<<<20480, 256, 0, stream>>>(data, Xb, 8192, 5000, 5120);
  cast_pad_kernel<<<1280, 256, 0, stream>>>(mlp_w, Wb, 512, 5000, 5120);
  // 2) MO = bias, then K-split GEMM1 accumulates atomically (z=5, 1280 blocks)
  init_bias<<<4096, 256, 0, stream>>>(mlp_b, MO);
  gemm1_split<<<1280, 256, 0, stream>>>(Xb, Wb, MO, 8192, 512, 5120, 1024);
  // 3) V = CM . cla_w  (Xb overlay now dead -> Vs lives there)
  cmv_kernel<<<2048, 256, 0, stream>>>(CM, cla_w, Vs);
  // 4) fused softmax + mixture-collapse + classifier + sigmoid
  attn_final<<<512, 256, 0, stream>>>(MO, attn, Vs, cla_b, out);
}